// Round 6
// baseline (373.081 us; speedup 1.0000x reference)
//
#include <hip/hip_runtime.h>

#define BDIM 256

constexpr int Cc = 32, Hh = 512, Ww = 640, HW = Hh * Ww, NBV = 8;
constexpr int TS = 32, TXN = Ww / TS, TYN = Hh / TS, NTILE = TXN * TYN; // 20x16=320

typedef float  fx4 __attribute__((ext_vector_type(4)));
typedef float  fx2 __attribute__((ext_vector_type(2)));
typedef unsigned int ux4 __attribute__((ext_vector_type(4)));
typedef unsigned int ux2 __attribute__((ext_vector_type(2)));

__device__ __forceinline__ unsigned short f32_to_bf16_rne(float f) {
    unsigned int u = __float_as_uint(f);
    u = (u + 0x7fffu + ((u >> 16) & 1u)) >> 16;
    return (unsigned short)u;
}

// one point's projection -> clamped corner coords + weights (zeros padding)
__device__ __forceinline__ void project_point(
    const float* Kp, const float* Ep,
    float px, float py, float pz,
    int& x0c, int& x1c, int& y0c, int& y1c, float* wgt)
{
    const float X = fmaf(Ep[0], px, fmaf(Ep[1], py, fmaf(Ep[2], pz, Ep[3])));
    const float Y = fmaf(Ep[4], px, fmaf(Ep[5], py, fmaf(Ep[6], pz, Ep[7])));
    const float Z = fmaf(Ep[8], px, fmaf(Ep[9], py, fmaf(Ep[10], pz, Ep[11])));
    const bool zzero = (Z == 0.0f);
    const float zs = zzero ? 1.0f : Z;
    const float xn = X / zs;
    const float yn = Y / zs;
    float u = fmaf(Kp[0], xn, fmaf(Kp[1], yn, Kp[2]));
    float v = fmaf(Kp[3], xn, fmaf(Kp[4], yn, Kp[5]));
    if (zzero) { u = 2.0f * Ww; v = 2.0f * Hh; }
    const float ix = u - 0.5f;
    const float iy = v - 0.5f;
    const float x0f = floorf(ix);
    const float y0f = floorf(iy);
    const float wx1 = ix - x0f, wx0 = 1.0f - wx1;
    const float wy1 = iy - y0f, wy0 = 1.0f - wy1;
    const bool vx0 = (x0f >= 0.0f)  && (x0f <= (float)(Ww - 1));
    const bool vx1 = (x0f >= -1.0f) && (x0f <= (float)(Ww - 2));
    const bool vy0 = (y0f >= 0.0f)  && (y0f <= (float)(Hh - 1));
    const bool vy1 = (y0f >= -1.0f) && (y0f <= (float)(Hh - 2));
    x0c = (int)fminf(fmaxf(x0f,        0.0f), (float)(Ww - 1));
    x1c = (int)fminf(fmaxf(x0f + 1.0f, 0.0f), (float)(Ww - 1));
    y0c = (int)fminf(fmaxf(y0f,        0.0f), (float)(Hh - 1));
    y1c = (int)fminf(fmaxf(y0f + 1.0f, 0.0f), (float)(Hh - 1));
    wgt[0] = wx0 * wy0 * ((vx0 && vy0) ? 1.0f : 0.0f);
    wgt[1] = wx1 * wy0 * ((vx1 && vy0) ? 1.0f : 0.0f);
    wgt[2] = wx0 * wy1 * ((vx0 && vy1) ? 1.0f : 0.0f);
    wgt[3] = wx1 * wy1 * ((vx1 && vy1) ? 1.0f : 0.0f);
}

// mark the <=4 tiles the clamped corners of each point-view touch
__global__ __launch_bounds__(256) void mark_kernel(
    const float* __restrict__ pts,
    const float* __restrict__ Kmat,
    const float* __restrict__ Emat,
    unsigned int* __restrict__ bitmap,
    int N)
{
    const int bv = blockIdx.y;
    const int b  = bv >> 2;
    const int n  = blockIdx.x * 256 + threadIdx.x;
    if (n >= N) return;
    int x0c, x1c, y0c, y1c; float w[4];
    project_point(Kmat + bv * 9, Emat + bv * 12,
                  pts[(size_t)(b * 3 + 0) * N + n],
                  pts[(size_t)(b * 3 + 1) * N + n],
                  pts[(size_t)(b * 3 + 2) * N + n],
                  x0c, x1c, y0c, y1c, w);
    const int tx0 = x0c >> 5, tx1 = x1c >> 5;
    const int ty0 = y0c >> 5, ty1 = y1c >> 5;
    unsigned int* bm = bitmap + bv * NTILE;
    unsigned int* p0 = &bm[ty0 * TXN + tx0];
    if (*p0 == 0u) atomicOr(p0, 1u);
    if (tx1 != tx0) { unsigned int* p = &bm[ty0 * TXN + tx1]; if (*p == 0u) atomicOr(p, 1u); }
    if (ty1 != ty0) {
        unsigned int* p = &bm[ty1 * TXN + tx0]; if (*p == 0u) atomicOr(p, 1u);
        if (tx1 != tx0) { unsigned int* p2 = &bm[ty1 * TXN + tx1]; if (*p2 == 0u) atomicOr(p2, 1u); }
    }
}

// per-tile transpose: fm [BV][C][H][W] f32 -> ws [BV][H*W][C] bf16,
// skipping tiles no corner ever touches.
__global__ __launch_bounds__(256) void transpose_tiles_kernel(
    const float* __restrict__ fm, unsigned short* __restrict__ ws,
    const unsigned int* __restrict__ bitmap)
{
    const int bv = blockIdx.y;
    const int t  = blockIdx.x;
    if (!bitmap[bv * NTILE + t]) return;

    const int ty = t / TXN, tx = t - ty * TXN;
    const int y0 = ty * TS, x0 = tx * TS;

    // lds[pixel][c] with 36-short record stride (8B-aligned, 2-way banks max)
    __shared__ unsigned short lds[TS * TS * 36];

    const int tid = threadIdx.x;
    const float* src = fm + (size_t)bv * Cc * HW;

    // load: lanes = (x2 0..15, yh 0..15); per c, rows yh and yh+16
    const int x2 = tid & 15, yh = tid >> 4;
    #pragma unroll
    for (int c = 0; c < Cc; ++c) {
        #pragma unroll
        for (int k = 0; k < 2; ++k) {
            const int y = yh + 16 * k;
            fx2 v = __builtin_nontemporal_load(
                (const fx2*)&src[(size_t)c * HW + (size_t)(y0 + y) * Ww + x0 + 2 * x2]);
            lds[(y * TS + 2 * x2 + 0) * 36 + c] = f32_to_bf16_rne(v[0]);
            lds[(y * TS + 2 * x2 + 1) * 36 + c] = f32_to_bf16_rne(v[1]);
        }
    }
    __syncthreads();

    // store: lanes = (c4 0..3 owning 8 channels, p 0..63); 16 iterations
    const int c4 = tid & 3, pb = tid >> 2;
    #pragma unroll
    for (int it = 0; it < 16; ++it) {
        const int pp = it * 64 + pb;
        const int y = pp >> 5, x = pp & 31;
        const ux2 lo = *(const ux2*)&lds[pp * 36 + 8 * c4];
        const ux2 hi = *(const ux2*)&lds[pp * 36 + 8 * c4 + 4];
        ux4 o; o[0] = lo[0]; o[1] = lo[1]; o[2] = hi[0]; o[3] = hi[1];
        unsigned short* dst = ws + ((size_t)bv * HW + (size_t)(y0 + y) * Ww + x0 + x) * Cc + 8 * c4;
        *(ux4*)dst = o;
    }
}

// legacy full transpose (mid fallback): fm -> ws, strip-based
__global__ __launch_bounds__(256) void transpose_kernel(
    const float* __restrict__ fm, unsigned short* __restrict__ ws)
{
    __shared__ float lds[32 * 260];
    const int bv  = blockIdx.y;
    const int p0  = blockIdx.x * 256;
    const int tid = threadIdx.x;
    const int m   = tid & 63;
    const int g   = tid >> 6;
    const fx4* src = (const fx4*)(fm + (size_t)bv * Cc * HW);
    #pragma unroll
    for (int it = 0; it < 8; ++it) {
        const int c = it * 4 + g;
        fx4 v = __builtin_nontemporal_load(&src[(size_t)((c * HW + p0) >> 2) + m]);
        *(fx4*)&lds[c * 260 + 4 * m] = v;
    }
    __syncthreads();
    const int q     = tid & 7;
    const int pbase = tid >> 3;
    unsigned short* dst = ws + ((size_t)bv * HW + p0) * Cc;
    #pragma unroll
    for (int it = 0; it < 8; ++it) {
        const int pp = it * 32 + pbase;
        ushort4 o;
        o.x = f32_to_bf16_rne(lds[(4 * q + 0) * 260 + pp]);
        o.y = f32_to_bf16_rne(lds[(4 * q + 1) * 260 + pp]);
        o.z = f32_to_bf16_rne(lds[(4 * q + 2) * 260 + pp]);
        o.w = f32_to_bf16_rne(lds[(4 * q + 3) * 260 + pp]);
        *(ushort4*)&dst[(size_t)pp * Cc + 4 * q] = o;
    }
}

// Quad-cooperative, 2 points per thread (unchanged from R5)
__global__ __launch_bounds__(BDIM) void gather2_kernel(
    const unsigned short* __restrict__ ws,
    const float* __restrict__ pts,
    const float* __restrict__ Kmat,
    const float* __restrict__ Emat,
    float* __restrict__ out,
    int N)
{
    const int bv  = blockIdx.y;
    const int b   = bv >> 2;
    const int tid = threadIdx.x;
    const int q   = tid & 3;
    const int n0  = (blockIdx.x * (BDIM / 4) + (tid >> 2)) * 2;
    if (n0 >= N) return;

    const float* Kp = Kmat + bv * 9;
    const float* Ep = Emat + bv * 12;

    const fx2 pxv = *(const fx2*)&pts[(size_t)(b * 3 + 0) * N + n0];
    const fx2 pyv = *(const fx2*)&pts[(size_t)(b * 3 + 1) * N + n0];
    const fx2 pzv = *(const fx2*)&pts[(size_t)(b * 3 + 2) * N + n0];

    int   idx[2][4];
    float wgt[2][4];
    #pragma unroll
    for (int t = 0; t < 2; ++t) {
        int x0c, x1c, y0c, y1c;
        project_point(Kp, Ep, pxv[t], pyv[t], pzv[t], x0c, x1c, y0c, y1c, wgt[t]);
        idx[t][0] = y0c * Ww + x0c;
        idx[t][1] = y0c * Ww + x1c;
        idx[t][2] = y1c * Ww + x0c;
        idx[t][3] = y1c * Ww + x1c;
    }

    const unsigned short* base = ws + (size_t)bv * HW * Cc + q * 8;

    float acc[2][8];
    #pragma unroll
    for (int t = 0; t < 2; ++t)
        #pragma unroll
        for (int j = 0; j < 8; ++j) acc[t][j] = 0.0f;

    #pragma unroll
    for (int t = 0; t < 2; ++t) {
        #pragma unroll
        for (int k = 0; k < 4; ++k) {
            const ux4 vv = *(const ux4*)(base + (size_t)idx[t][k] * Cc);
            const float w = wgt[t][k];
            #pragma unroll
            for (int j = 0; j < 4; ++j) {
                const unsigned int uu = vv[j];
                acc[t][2*j+0] = fmaf(__uint_as_float(uu << 16),         w, acc[t][2*j+0]);
                acc[t][2*j+1] = fmaf(__uint_as_float(uu & 0xffff0000u), w, acc[t][2*j+1]);
            }
        }
    }

    float* obase = out + (size_t)bv * Cc * N + (size_t)(8 * q) * N + n0;
    #pragma unroll
    for (int j = 0; j < 8; ++j) {
        fx2 o = { acc[0][j], acc[1][j] };
        __builtin_nontemporal_store(o, (fx2*)&obase[(size_t)j * N]);
    }
}

// 1-pt/thread variant (odd N)
__global__ __launch_bounds__(BDIM) void gather_kernel(
    const unsigned short* __restrict__ ws,
    const float* __restrict__ pts,
    const float* __restrict__ Kmat,
    const float* __restrict__ Emat,
    float* __restrict__ out,
    int N)
{
    const int bv  = blockIdx.y;
    const int b   = bv >> 2;
    const int tid = threadIdx.x;
    const int q   = tid & 3;
    const int n   = blockIdx.x * (BDIM / 4) + (tid >> 2);
    if (n >= N) return;

    int x0c, x1c, y0c, y1c; float wgt[4];
    project_point(Kmat + bv * 9, Emat + bv * 12,
                  pts[(size_t)(b * 3 + 0) * N + n],
                  pts[(size_t)(b * 3 + 1) * N + n],
                  pts[(size_t)(b * 3 + 2) * N + n],
                  x0c, x1c, y0c, y1c, wgt);
    const int idx[4] = { y0c * Ww + x0c, y0c * Ww + x1c,
                         y1c * Ww + x0c, y1c * Ww + x1c };

    const unsigned short* base = ws + (size_t)bv * HW * Cc + q * 8;
    float acc[8];
    #pragma unroll
    for (int j = 0; j < 8; ++j) acc[j] = 0.0f;

    #pragma unroll
    for (int k = 0; k < 4; ++k) {
        const ux4 vv = *(const ux4*)(base + (size_t)idx[k] * Cc);
        const float w = wgt[k];
        #pragma unroll
        for (int j = 0; j < 4; ++j) {
            const unsigned int uu = vv[j];
            acc[2*j+0] = fmaf(__uint_as_float(uu << 16),         w, acc[2*j+0]);
            acc[2*j+1] = fmaf(__uint_as_float(uu & 0xffff0000u), w, acc[2*j+1]);
        }
    }

    float* obase = out + (size_t)bv * Cc * N + (size_t)(8 * q) * N + n;
    #pragma unroll
    for (int j = 0; j < 8; ++j)
        __builtin_nontemporal_store(acc[j], &obase[(size_t)j * N]);
}

// full fallback (no workspace)
__global__ __launch_bounds__(BDIM) void feature_fetch_fallback(
    const float* __restrict__ fm, const float* __restrict__ pts,
    const float* __restrict__ Kmat, const float* __restrict__ Emat,
    float* __restrict__ out, int N)
{
    const int bv = blockIdx.y;
    const int b  = bv >> 2;
    const int n  = blockIdx.x * BDIM + threadIdx.x;
    if (n >= N) return;
    int x0c, x1c, y0c, y1c; float wgt[4];
    project_point(Kmat + bv * 9, Emat + bv * 12,
                  pts[(size_t)(b * 3 + 0) * N + n],
                  pts[(size_t)(b * 3 + 1) * N + n],
                  pts[(size_t)(b * 3 + 2) * N + n],
                  x0c, x1c, y0c, y1c, wgt);
    const int idx[4] = { y0c * Ww + x0c, y0c * Ww + x1c,
                         y1c * Ww + x0c, y1c * Ww + x1c };
    const float* basep = fm + (size_t)bv * Cc * HW;
    float* obase = out + (size_t)bv * Cc * N + n;
    #pragma unroll 4
    for (int c = 0; c < Cc; ++c) {
        const float* p = basep + (size_t)c * HW;
        obase[(size_t)c * N] = p[idx[0]] * wgt[0] + p[idx[1]] * wgt[1]
                             + p[idx[2]] * wgt[2] + p[idx[3]] * wgt[3];
    }
}

extern "C" void kernel_launch(void* const* d_in, const int* in_sizes, int n_in,
                              void* d_out, int out_size, void* d_ws, size_t ws_size,
                              hipStream_t stream) {
    const float* fm  = (const float*)d_in[0];
    const float* pts = (const float*)d_in[1];
    const float* K   = (const float*)d_in[2];
    const float* E   = (const float*)d_in[3];
    float* out = (float*)d_out;
    const int N = in_sizes[1] / 6;   // pts is [B=2, 3, N]

    const size_t tiles_bytes = (size_t)NBV * HW * Cc * sizeof(unsigned short); // 160 MB
    const size_t bm_bytes    = (size_t)NBV * NTILE * sizeof(unsigned int);     // 10 KB

    if (ws_size >= tiles_bytes + bm_bytes) {
        unsigned short* ws = (unsigned short*)d_ws;
        unsigned int* bitmap = (unsigned int*)((char*)d_ws + tiles_bytes);

        hipMemsetAsync(bitmap, 0, bm_bytes, stream);
        dim3 mgrid((N + 255) / 256, NBV);
        mark_kernel<<<mgrid, 256, 0, stream>>>(pts, K, E, bitmap, N);
        dim3 tgrid(NTILE, NBV);
        transpose_tiles_kernel<<<tgrid, 256, 0, stream>>>(fm, ws, bitmap);

        if ((N & 1) == 0) {
            const int ppb = (BDIM / 4) * 2;
            dim3 ggrid((N + ppb - 1) / ppb, NBV);
            gather2_kernel<<<ggrid, BDIM, 0, stream>>>(ws, pts, K, E, out, N);
        } else {
            const int ppb = BDIM / 4;
            dim3 ggrid((N + ppb - 1) / ppb, NBV);
            gather_kernel<<<ggrid, BDIM, 0, stream>>>(ws, pts, K, E, out, N);
        }
    } else if (ws_size >= tiles_bytes) {
        unsigned short* ws = (unsigned short*)d_ws;
        dim3 tgrid(HW / 256, NBV);
        transpose_kernel<<<tgrid, 256, 0, stream>>>(fm, ws);
        if ((N & 1) == 0) {
            const int ppb = (BDIM / 4) * 2;
            dim3 ggrid((N + ppb - 1) / ppb, NBV);
            gather2_kernel<<<ggrid, BDIM, 0, stream>>>(ws, pts, K, E, out, N);
        } else {
            const int ppb = BDIM / 4;
            dim3 ggrid((N + ppb - 1) / ppb, NBV);
            gather_kernel<<<ggrid, BDIM, 0, stream>>>(ws, pts, K, E, out, N);
        }
    } else {
        dim3 grid((N + BDIM - 1) / BDIM, NBV);
        feature_fetch_fallback<<<grid, BDIM, 0, stream>>>(fm, pts, K, E, out, N);
    }
}

// Round 7
// 181.746 us; speedup vs baseline: 2.0528x; 2.0528x over previous
//
#include <hip/hip_runtime.h>

#define BDIM 256

constexpr int Cc = 32, Hh = 512, Ww = 640, HW = Hh * Ww, NBV = 8;
constexpr int TS = 32, TXN = Ww / TS, TYN = Hh / TS, NTILE = TXN * TYN; // 20x16=320

typedef float  fx4 __attribute__((ext_vector_type(4)));
typedef float  fx2 __attribute__((ext_vector_type(2)));
typedef unsigned int ux4 __attribute__((ext_vector_type(4)));
typedef unsigned int ux2 __attribute__((ext_vector_type(2)));

__device__ __forceinline__ unsigned short f32_to_bf16_rne(float f) {
    unsigned int u = __float_as_uint(f);
    u = (u + 0x7fffu + ((u >> 16) & 1u)) >> 16;
    return (unsigned short)u;
}

// one point's projection -> clamped corner coords + weights (zeros padding)
__device__ __forceinline__ void project_point(
    const float* Kp, const float* Ep,
    float px, float py, float pz,
    int& x0c, int& x1c, int& y0c, int& y1c, float* wgt)
{
    const float X = fmaf(Ep[0], px, fmaf(Ep[1], py, fmaf(Ep[2], pz, Ep[3])));
    const float Y = fmaf(Ep[4], px, fmaf(Ep[5], py, fmaf(Ep[6], pz, Ep[7])));
    const float Z = fmaf(Ep[8], px, fmaf(Ep[9], py, fmaf(Ep[10], pz, Ep[11])));
    const bool zzero = (Z == 0.0f);
    const float zs = zzero ? 1.0f : Z;
    const float xn = X / zs;
    const float yn = Y / zs;
    float u = fmaf(Kp[0], xn, fmaf(Kp[1], yn, Kp[2]));
    float v = fmaf(Kp[3], xn, fmaf(Kp[4], yn, Kp[5]));
    if (zzero) { u = 2.0f * Ww; v = 2.0f * Hh; }
    const float ix = u - 0.5f;
    const float iy = v - 0.5f;
    const float x0f = floorf(ix);
    const float y0f = floorf(iy);
    const float wx1 = ix - x0f, wx0 = 1.0f - wx1;
    const float wy1 = iy - y0f, wy0 = 1.0f - wy1;
    const bool vx0 = (x0f >= 0.0f)  && (x0f <= (float)(Ww - 1));
    const bool vx1 = (x0f >= -1.0f) && (x0f <= (float)(Ww - 2));
    const bool vy0 = (y0f >= 0.0f)  && (y0f <= (float)(Hh - 1));
    const bool vy1 = (y0f >= -1.0f) && (y0f <= (float)(Hh - 2));
    x0c = (int)fminf(fmaxf(x0f,        0.0f), (float)(Ww - 1));
    x1c = (int)fminf(fmaxf(x0f + 1.0f, 0.0f), (float)(Ww - 1));
    y0c = (int)fminf(fmaxf(y0f,        0.0f), (float)(Hh - 1));
    y1c = (int)fminf(fmaxf(y0f + 1.0f, 0.0f), (float)(Hh - 1));
    wgt[0] = wx0 * wy0 * ((vx0 && vy0) ? 1.0f : 0.0f);
    wgt[1] = wx1 * wy0 * ((vx1 && vy0) ? 1.0f : 0.0f);
    wgt[2] = wx0 * wy1 * ((vx0 && vy1) ? 1.0f : 0.0f);
    wgt[3] = wx1 * wy1 * ((vx1 && vy1) ? 1.0f : 0.0f);
}

// LDS-aggregated tile marking: block-local bitmap, then few global atomics.
__global__ __launch_bounds__(256) void mark_kernel(
    const float* __restrict__ pts,
    const float* __restrict__ Kmat,
    const float* __restrict__ Emat,
    unsigned int* __restrict__ bitmap,
    int N, int per_block)
{
    __shared__ unsigned int sbm[NTILE];
    const int bv = blockIdx.y;
    const int b  = bv >> 2;
    for (int i = threadIdx.x; i < NTILE; i += 256) sbm[i] = 0u;
    __syncthreads();

    const float* Kp = Kmat + bv * 9;
    const float* Ep = Emat + bv * 12;
    const int start = blockIdx.x * per_block;
    const int end   = min(start + per_block, N);
    for (int n = start + (int)threadIdx.x; n < end; n += 256) {
        int x0c, x1c, y0c, y1c; float w[4];
        project_point(Kp, Ep,
                      pts[(size_t)(b * 3 + 0) * N + n],
                      pts[(size_t)(b * 3 + 1) * N + n],
                      pts[(size_t)(b * 3 + 2) * N + n],
                      x0c, x1c, y0c, y1c, w);
        const int tx0 = x0c >> 5, tx1 = x1c >> 5;
        const int ty0 = y0c >> 5, ty1 = y1c >> 5;
        atomicOr(&sbm[ty0 * TXN + tx0], 1u);
        if (tx1 != tx0) atomicOr(&sbm[ty0 * TXN + tx1], 1u);
        if (ty1 != ty0) {
            atomicOr(&sbm[ty1 * TXN + tx0], 1u);
            if (tx1 != tx0) atomicOr(&sbm[ty1 * TXN + tx1], 1u);
        }
    }
    __syncthreads();

    unsigned int* bm = bitmap + bv * NTILE;
    for (int i = threadIdx.x; i < NTILE; i += 256) {
        // global read guard: skip atomic if already visibly set (stale-0 is
        // harmless — just one extra atomic)
        if (sbm[i] && bm[i] == 0u) atomicOr(&bm[i], 1u);
    }
}

// per-tile transpose: fm [BV][C][H][W] f32 -> ws [BV][H*W][C] bf16,
// skipping tiles no corner ever touches.
__global__ __launch_bounds__(256) void transpose_tiles_kernel(
    const float* __restrict__ fm, unsigned short* __restrict__ ws,
    const unsigned int* __restrict__ bitmap)
{
    const int bv = blockIdx.y;
    const int t  = blockIdx.x;
    if (!bitmap[bv * NTILE + t]) return;

    const int ty = t / TXN, tx = t - ty * TXN;
    const int y0 = ty * TS, x0 = tx * TS;

    __shared__ unsigned short lds[TS * TS * 36];

    const int tid = threadIdx.x;
    const float* src = fm + (size_t)bv * Cc * HW;

    const int x2 = tid & 15, yh = tid >> 4;
    #pragma unroll
    for (int c = 0; c < Cc; ++c) {
        #pragma unroll
        for (int k = 0; k < 2; ++k) {
            const int y = yh + 16 * k;
            fx2 v = __builtin_nontemporal_load(
                (const fx2*)&src[(size_t)c * HW + (size_t)(y0 + y) * Ww + x0 + 2 * x2]);
            lds[(y * TS + 2 * x2 + 0) * 36 + c] = f32_to_bf16_rne(v[0]);
            lds[(y * TS + 2 * x2 + 1) * 36 + c] = f32_to_bf16_rne(v[1]);
        }
    }
    __syncthreads();

    const int c4 = tid & 3, pb = tid >> 2;
    #pragma unroll
    for (int it = 0; it < 16; ++it) {
        const int pp = it * 64 + pb;
        const int y = pp >> 5, x = pp & 31;
        const ux2 lo = *(const ux2*)&lds[pp * 36 + 8 * c4];
        const ux2 hi = *(const ux2*)&lds[pp * 36 + 8 * c4 + 4];
        ux4 o; o[0] = lo[0]; o[1] = lo[1]; o[2] = hi[0]; o[3] = hi[1];
        unsigned short* dst = ws + ((size_t)bv * HW + (size_t)(y0 + y) * Ww + x0 + x) * Cc + 8 * c4;
        *(ux4*)dst = o;
    }
}

// legacy full transpose (mid fallback)
__global__ __launch_bounds__(256) void transpose_kernel(
    const float* __restrict__ fm, unsigned short* __restrict__ ws)
{
    __shared__ float lds[32 * 260];
    const int bv  = blockIdx.y;
    const int p0  = blockIdx.x * 256;
    const int tid = threadIdx.x;
    const int m   = tid & 63;
    const int g   = tid >> 6;
    const fx4* src = (const fx4*)(fm + (size_t)bv * Cc * HW);
    #pragma unroll
    for (int it = 0; it < 8; ++it) {
        const int c = it * 4 + g;
        fx4 v = __builtin_nontemporal_load(&src[(size_t)((c * HW + p0) >> 2) + m]);
        *(fx4*)&lds[c * 260 + 4 * m] = v;
    }
    __syncthreads();
    const int q     = tid & 7;
    const int pbase = tid >> 3;
    unsigned short* dst = ws + ((size_t)bv * HW + p0) * Cc;
    #pragma unroll
    for (int it = 0; it < 8; ++it) {
        const int pp = it * 32 + pbase;
        ushort4 o;
        o.x = f32_to_bf16_rne(lds[(4 * q + 0) * 260 + pp]);
        o.y = f32_to_bf16_rne(lds[(4 * q + 1) * 260 + pp]);
        o.z = f32_to_bf16_rne(lds[(4 * q + 2) * 260 + pp]);
        o.w = f32_to_bf16_rne(lds[(4 * q + 3) * 260 + pp]);
        *(ushort4*)&dst[(size_t)pp * Cc + 4 * q] = o;
    }
}

// Quad-cooperative, 2 points per thread
__global__ __launch_bounds__(BDIM) void gather2_kernel(
    const unsigned short* __restrict__ ws,
    const float* __restrict__ pts,
    const float* __restrict__ Kmat,
    const float* __restrict__ Emat,
    float* __restrict__ out,
    int N)
{
    const int bv  = blockIdx.y;
    const int b   = bv >> 2;
    const int tid = threadIdx.x;
    const int q   = tid & 3;
    const int n0  = (blockIdx.x * (BDIM / 4) + (tid >> 2)) * 2;
    if (n0 >= N) return;

    const float* Kp = Kmat + bv * 9;
    const float* Ep = Emat + bv * 12;

    const fx2 pxv = *(const fx2*)&pts[(size_t)(b * 3 + 0) * N + n0];
    const fx2 pyv = *(const fx2*)&pts[(size_t)(b * 3 + 1) * N + n0];
    const fx2 pzv = *(const fx2*)&pts[(size_t)(b * 3 + 2) * N + n0];

    int   idx[2][4];
    float wgt[2][4];
    #pragma unroll
    for (int t = 0; t < 2; ++t) {
        int x0c, x1c, y0c, y1c;
        project_point(Kp, Ep, pxv[t], pyv[t], pzv[t], x0c, x1c, y0c, y1c, wgt[t]);
        idx[t][0] = y0c * Ww + x0c;
        idx[t][1] = y0c * Ww + x1c;
        idx[t][2] = y1c * Ww + x0c;
        idx[t][3] = y1c * Ww + x1c;
    }

    const unsigned short* base = ws + (size_t)bv * HW * Cc + q * 8;

    float acc[2][8];
    #pragma unroll
    for (int t = 0; t < 2; ++t)
        #pragma unroll
        for (int j = 0; j < 8; ++j) acc[t][j] = 0.0f;

    #pragma unroll
    for (int t = 0; t < 2; ++t) {
        #pragma unroll
        for (int k = 0; k < 4; ++k) {
            const ux4 vv = *(const ux4*)(base + (size_t)idx[t][k] * Cc);
            const float w = wgt[t][k];
            #pragma unroll
            for (int j = 0; j < 4; ++j) {
                const unsigned int uu = vv[j];
                acc[t][2*j+0] = fmaf(__uint_as_float(uu << 16),         w, acc[t][2*j+0]);
                acc[t][2*j+1] = fmaf(__uint_as_float(uu & 0xffff0000u), w, acc[t][2*j+1]);
            }
        }
    }

    float* obase = out + (size_t)bv * Cc * N + (size_t)(8 * q) * N + n0;
    #pragma unroll
    for (int j = 0; j < 8; ++j) {
        fx2 o = { acc[0][j], acc[1][j] };
        __builtin_nontemporal_store(o, (fx2*)&obase[(size_t)j * N]);
    }
}

// 1-pt/thread variant (odd N)
__global__ __launch_bounds__(BDIM) void gather_kernel(
    const unsigned short* __restrict__ ws,
    const float* __restrict__ pts,
    const float* __restrict__ Kmat,
    const float* __restrict__ Emat,
    float* __restrict__ out,
    int N)
{
    const int bv  = blockIdx.y;
    const int b   = bv >> 2;
    const int tid = threadIdx.x;
    const int q   = tid & 3;
    const int n   = blockIdx.x * (BDIM / 4) + (tid >> 2);
    if (n >= N) return;

    int x0c, x1c, y0c, y1c; float wgt[4];
    project_point(Kmat + bv * 9, Emat + bv * 12,
                  pts[(size_t)(b * 3 + 0) * N + n],
                  pts[(size_t)(b * 3 + 1) * N + n],
                  pts[(size_t)(b * 3 + 2) * N + n],
                  x0c, x1c, y0c, y1c, wgt);
    const int idx[4] = { y0c * Ww + x0c, y0c * Ww + x1c,
                         y1c * Ww + x0c, y1c * Ww + x1c };

    const unsigned short* base = ws + (size_t)bv * HW * Cc + q * 8;
    float acc[8];
    #pragma unroll
    for (int j = 0; j < 8; ++j) acc[j] = 0.0f;

    #pragma unroll
    for (int k = 0; k < 4; ++k) {
        const ux4 vv = *(const ux4*)(base + (size_t)idx[k] * Cc);
        const float w = wgt[k];
        #pragma unroll
        for (int j = 0; j < 4; ++j) {
            const unsigned int uu = vv[j];
            acc[2*j+0] = fmaf(__uint_as_float(uu << 16),         w, acc[2*j+0]);
            acc[2*j+1] = fmaf(__uint_as_float(uu & 0xffff0000u), w, acc[2*j+1]);
        }
    }

    float* obase = out + (size_t)bv * Cc * N + (size_t)(8 * q) * N + n;
    #pragma unroll
    for (int j = 0; j < 8; ++j)
        __builtin_nontemporal_store(acc[j], &obase[(size_t)j * N]);
}

// full fallback (no workspace)
__global__ __launch_bounds__(BDIM) void feature_fetch_fallback(
    const float* __restrict__ fm, const float* __restrict__ pts,
    const float* __restrict__ Kmat, const float* __restrict__ Emat,
    float* __restrict__ out, int N)
{
    const int bv = blockIdx.y;
    const int b  = bv >> 2;
    const int n  = blockIdx.x * BDIM + threadIdx.x;
    if (n >= N) return;
    int x0c, x1c, y0c, y1c; float wgt[4];
    project_point(Kmat + bv * 9, Emat + bv * 12,
                  pts[(size_t)(b * 3 + 0) * N + n],
                  pts[(size_t)(b * 3 + 1) * N + n],
                  pts[(size_t)(b * 3 + 2) * N + n],
                  x0c, x1c, y0c, y1c, wgt);
    const int idx[4] = { y0c * Ww + x0c, y0c * Ww + x1c,
                         y1c * Ww + x0c, y1c * Ww + x1c };
    const float* basep = fm + (size_t)bv * Cc * HW;
    float* obase = out + (size_t)bv * Cc * N + n;
    #pragma unroll 4
    for (int c = 0; c < Cc; ++c) {
        const float* p = basep + (size_t)c * HW;
        obase[(size_t)c * N] = p[idx[0]] * wgt[0] + p[idx[1]] * wgt[1]
                             + p[idx[2]] * wgt[2] + p[idx[3]] * wgt[3];
    }
}

extern "C" void kernel_launch(void* const* d_in, const int* in_sizes, int n_in,
                              void* d_out, int out_size, void* d_ws, size_t ws_size,
                              hipStream_t stream) {
    const float* fm  = (const float*)d_in[0];
    const float* pts = (const float*)d_in[1];
    const float* K   = (const float*)d_in[2];
    const float* E   = (const float*)d_in[3];
    float* out = (float*)d_out;
    const int N = in_sizes[1] / 6;   // pts is [B=2, 3, N]

    const size_t tiles_bytes = (size_t)NBV * HW * Cc * sizeof(unsigned short); // 160 MB
    const size_t bm_bytes    = (size_t)NBV * NTILE * sizeof(unsigned int);     // 10 KB

    if (ws_size >= tiles_bytes + bm_bytes) {
        unsigned short* ws = (unsigned short*)d_ws;
        unsigned int* bitmap = (unsigned int*)((char*)d_ws + tiles_bytes);

        hipMemsetAsync(bitmap, 0, bm_bytes, stream);
        const int per_block = 2048;
        dim3 mgrid((N + per_block - 1) / per_block, NBV);
        mark_kernel<<<mgrid, 256, 0, stream>>>(pts, K, E, bitmap, N, per_block);
        dim3 tgrid(NTILE, NBV);
        transpose_tiles_kernel<<<tgrid, 256, 0, stream>>>(fm, ws, bitmap);

        if ((N & 1) == 0) {
            const int ppb = (BDIM / 4) * 2;
            dim3 ggrid((N + ppb - 1) / ppb, NBV);
            gather2_kernel<<<ggrid, BDIM, 0, stream>>>(ws, pts, K, E, out, N);
        } else {
            const int ppb = BDIM / 4;
            dim3 ggrid((N + ppb - 1) / ppb, NBV);
            gather_kernel<<<ggrid, BDIM, 0, stream>>>(ws, pts, K, E, out, N);
        }
    } else if (ws_size >= tiles_bytes) {
        unsigned short* ws = (unsigned short*)d_ws;
        dim3 tgrid(HW / 256, NBV);
        transpose_kernel<<<tgrid, 256, 0, stream>>>(fm, ws);
        if ((N & 1) == 0) {
            const int ppb = (BDIM / 4) * 2;
            dim3 ggrid((N + ppb - 1) / ppb, NBV);
            gather2_kernel<<<ggrid, BDIM, 0, stream>>>(ws, pts, K, E, out, N);
        } else {
            const int ppb = BDIM / 4;
            dim3 ggrid((N + ppb - 1) / ppb, NBV);
            gather_kernel<<<ggrid, BDIM, 0, stream>>>(ws, pts, K, E, out, N);
        }
    } else {
        dim3 grid((N + BDIM - 1) / BDIM, NBV);
        feature_fetch_fallback<<<grid, BDIM, 0, stream>>>(fm, pts, K, E, out, N);
    }
}

// Round 8
// 179.210 us; speedup vs baseline: 2.0818x; 1.0142x over previous
//
#include <hip/hip_runtime.h>

#define BDIM 256

constexpr int Cc = 32, Hh = 512, Ww = 640, HW = Hh * Ww, NBV = 8;
constexpr int TS = 32, TXN = Ww / TS, TYN = Hh / TS, NTILE = TXN * TYN; // 20x16=320

typedef float  fx4 __attribute__((ext_vector_type(4)));
typedef float  fx2 __attribute__((ext_vector_type(2)));
typedef unsigned int ux4 __attribute__((ext_vector_type(4)));
typedef unsigned int ux2 __attribute__((ext_vector_type(2)));

__device__ __forceinline__ unsigned short f32_to_bf16_rne(float f) {
    unsigned int u = __float_as_uint(f);
    u = (u + 0x7fffu + ((u >> 16) & 1u)) >> 16;
    return (unsigned short)u;
}

// one point's projection -> clamped corner coords + weights (zeros padding)
__device__ __forceinline__ void project_point(
    const float* Kp, const float* Ep,
    float px, float py, float pz,
    int& x0c, int& x1c, int& y0c, int& y1c, float* wgt)
{
    const float X = fmaf(Ep[0], px, fmaf(Ep[1], py, fmaf(Ep[2], pz, Ep[3])));
    const float Y = fmaf(Ep[4], px, fmaf(Ep[5], py, fmaf(Ep[6], pz, Ep[7])));
    const float Z = fmaf(Ep[8], px, fmaf(Ep[9], py, fmaf(Ep[10], pz, Ep[11])));
    const bool zzero = (Z == 0.0f);
    const float zs = zzero ? 1.0f : Z;
    const float xn = X / zs;
    const float yn = Y / zs;
    float u = fmaf(Kp[0], xn, fmaf(Kp[1], yn, Kp[2]));
    float v = fmaf(Kp[3], xn, fmaf(Kp[4], yn, Kp[5]));
    if (zzero) { u = 2.0f * Ww; v = 2.0f * Hh; }
    const float ix = u - 0.5f;
    const float iy = v - 0.5f;
    const float x0f = floorf(ix);
    const float y0f = floorf(iy);
    const float wx1 = ix - x0f, wx0 = 1.0f - wx1;
    const float wy1 = iy - y0f, wy0 = 1.0f - wy1;
    const bool vx0 = (x0f >= 0.0f)  && (x0f <= (float)(Ww - 1));
    const bool vx1 = (x0f >= -1.0f) && (x0f <= (float)(Ww - 2));
    const bool vy0 = (y0f >= 0.0f)  && (y0f <= (float)(Hh - 1));
    const bool vy1 = (y0f >= -1.0f) && (y0f <= (float)(Hh - 2));
    x0c = (int)fminf(fmaxf(x0f,        0.0f), (float)(Ww - 1));
    x1c = (int)fminf(fmaxf(x0f + 1.0f, 0.0f), (float)(Ww - 1));
    y0c = (int)fminf(fmaxf(y0f,        0.0f), (float)(Hh - 1));
    y1c = (int)fminf(fmaxf(y0f + 1.0f, 0.0f), (float)(Hh - 1));
    wgt[0] = wx0 * wy0 * ((vx0 && vy0) ? 1.0f : 0.0f);
    wgt[1] = wx1 * wy0 * ((vx1 && vy0) ? 1.0f : 0.0f);
    wgt[2] = wx0 * wy1 * ((vx0 && vy1) ? 1.0f : 0.0f);
    wgt[3] = wx1 * wy1 * ((vx1 && vy1) ? 1.0f : 0.0f);
}

// Tile marking with NO atomics: the bitmap is idempotent (all writers store
// 1), so plain LDS stores (same-address lanes: one winner, 1 cycle) and
// plain global stores are race-benign. Kernel boundary publishes to the
// transpose kernel.
__global__ __launch_bounds__(256) void mark_kernel(
    const float* __restrict__ pts,
    const float* __restrict__ Kmat,
    const float* __restrict__ Emat,
    unsigned int* __restrict__ bitmap,
    int N, int per_block)
{
    __shared__ unsigned int sbm[NTILE];
    const int bv = blockIdx.y;
    const int b  = bv >> 2;
    for (int i = threadIdx.x; i < NTILE; i += 256) sbm[i] = 0u;
    __syncthreads();

    const float* Kp = Kmat + bv * 9;
    const float* Ep = Emat + bv * 12;
    const int start = blockIdx.x * per_block;
    const int end   = min(start + per_block, N);
    for (int n = start + (int)threadIdx.x; n < end; n += 256) {
        int x0c, x1c, y0c, y1c; float w[4];
        project_point(Kp, Ep,
                      pts[(size_t)(b * 3 + 0) * N + n],
                      pts[(size_t)(b * 3 + 1) * N + n],
                      pts[(size_t)(b * 3 + 2) * N + n],
                      x0c, x1c, y0c, y1c, w);
        const int tx0 = x0c >> 5, tx1 = x1c >> 5;
        const int ty0 = y0c >> 5, ty1 = y1c >> 5;
        sbm[ty0 * TXN + tx0] = 1u;
        if (tx1 != tx0) sbm[ty0 * TXN + tx1] = 1u;
        if (ty1 != ty0) {
            sbm[ty1 * TXN + tx0] = 1u;
            if (tx1 != tx0) sbm[ty1 * TXN + tx1] = 1u;
        }
    }
    __syncthreads();

    unsigned int* bm = bitmap + bv * NTILE;
    for (int i = threadIdx.x; i < NTILE; i += 256) {
        // read-guard to avoid hot-line store storms; plain store (value 1
        // from every writer -> benign race)
        if (sbm[i] && bm[i] == 0u) bm[i] = 1u;
    }
}

// per-tile transpose: fm [BV][C][H][W] f32 -> ws [BV][H*W][C] bf16,
// skipping tiles no corner ever touches.
__global__ __launch_bounds__(256) void transpose_tiles_kernel(
    const float* __restrict__ fm, unsigned short* __restrict__ ws,
    const unsigned int* __restrict__ bitmap)
{
    const int bv = blockIdx.y;
    const int t  = blockIdx.x;
    if (!bitmap[bv * NTILE + t]) return;

    const int ty = t / TXN, tx = t - ty * TXN;
    const int y0 = ty * TS, x0 = tx * TS;

    __shared__ unsigned short lds[TS * TS * 36];

    const int tid = threadIdx.x;
    const float* src = fm + (size_t)bv * Cc * HW;

    const int x2 = tid & 15, yh = tid >> 4;
    #pragma unroll
    for (int c = 0; c < Cc; ++c) {
        #pragma unroll
        for (int k = 0; k < 2; ++k) {
            const int y = yh + 16 * k;
            fx2 v = __builtin_nontemporal_load(
                (const fx2*)&src[(size_t)c * HW + (size_t)(y0 + y) * Ww + x0 + 2 * x2]);
            lds[(y * TS + 2 * x2 + 0) * 36 + c] = f32_to_bf16_rne(v[0]);
            lds[(y * TS + 2 * x2 + 1) * 36 + c] = f32_to_bf16_rne(v[1]);
        }
    }
    __syncthreads();

    const int c4 = tid & 3, pb = tid >> 2;
    #pragma unroll
    for (int it = 0; it < 16; ++it) {
        const int pp = it * 64 + pb;
        const int y = pp >> 5, x = pp & 31;
        const ux2 lo = *(const ux2*)&lds[pp * 36 + 8 * c4];
        const ux2 hi = *(const ux2*)&lds[pp * 36 + 8 * c4 + 4];
        ux4 o; o[0] = lo[0]; o[1] = lo[1]; o[2] = hi[0]; o[3] = hi[1];
        unsigned short* dst = ws + ((size_t)bv * HW + (size_t)(y0 + y) * Ww + x0 + x) * Cc + 8 * c4;
        *(ux4*)dst = o;
    }
}

// legacy full transpose (mid fallback)
__global__ __launch_bounds__(256) void transpose_kernel(
    const float* __restrict__ fm, unsigned short* __restrict__ ws)
{
    __shared__ float lds[32 * 260];
    const int bv  = blockIdx.y;
    const int p0  = blockIdx.x * 256;
    const int tid = threadIdx.x;
    const int m   = tid & 63;
    const int g   = tid >> 6;
    const fx4* src = (const fx4*)(fm + (size_t)bv * Cc * HW);
    #pragma unroll
    for (int it = 0; it < 8; ++it) {
        const int c = it * 4 + g;
        fx4 v = __builtin_nontemporal_load(&src[(size_t)((c * HW + p0) >> 2) + m]);
        *(fx4*)&lds[c * 260 + 4 * m] = v;
    }
    __syncthreads();
    const int q     = tid & 7;
    const int pbase = tid >> 3;
    unsigned short* dst = ws + ((size_t)bv * HW + p0) * Cc;
    #pragma unroll
    for (int it = 0; it < 8; ++it) {
        const int pp = it * 32 + pbase;
        ushort4 o;
        o.x = f32_to_bf16_rne(lds[(4 * q + 0) * 260 + pp]);
        o.y = f32_to_bf16_rne(lds[(4 * q + 1) * 260 + pp]);
        o.z = f32_to_bf16_rne(lds[(4 * q + 2) * 260 + pp]);
        o.w = f32_to_bf16_rne(lds[(4 * q + 3) * 260 + pp]);
        *(ushort4*)&dst[(size_t)pp * Cc + 4 * q] = o;
    }
}

// Quad-cooperative, 2 points per thread
__global__ __launch_bounds__(BDIM) void gather2_kernel(
    const unsigned short* __restrict__ ws,
    const float* __restrict__ pts,
    const float* __restrict__ Kmat,
    const float* __restrict__ Emat,
    float* __restrict__ out,
    int N)
{
    const int bv  = blockIdx.y;
    const int b   = bv >> 2;
    const int tid = threadIdx.x;
    const int q   = tid & 3;
    const int n0  = (blockIdx.x * (BDIM / 4) + (tid >> 2)) * 2;
    if (n0 >= N) return;

    const float* Kp = Kmat + bv * 9;
    const float* Ep = Emat + bv * 12;

    const fx2 pxv = *(const fx2*)&pts[(size_t)(b * 3 + 0) * N + n0];
    const fx2 pyv = *(const fx2*)&pts[(size_t)(b * 3 + 1) * N + n0];
    const fx2 pzv = *(const fx2*)&pts[(size_t)(b * 3 + 2) * N + n0];

    int   idx[2][4];
    float wgt[2][4];
    #pragma unroll
    for (int t = 0; t < 2; ++t) {
        int x0c, x1c, y0c, y1c;
        project_point(Kp, Ep, pxv[t], pyv[t], pzv[t], x0c, x1c, y0c, y1c, wgt[t]);
        idx[t][0] = y0c * Ww + x0c;
        idx[t][1] = y0c * Ww + x1c;
        idx[t][2] = y1c * Ww + x0c;
        idx[t][3] = y1c * Ww + x1c;
    }

    const unsigned short* base = ws + (size_t)bv * HW * Cc + q * 8;

    float acc[2][8];
    #pragma unroll
    for (int t = 0; t < 2; ++t)
        #pragma unroll
        for (int j = 0; j < 8; ++j) acc[t][j] = 0.0f;

    #pragma unroll
    for (int t = 0; t < 2; ++t) {
        #pragma unroll
        for (int k = 0; k < 4; ++k) {
            const ux4 vv = *(const ux4*)(base + (size_t)idx[t][k] * Cc);
            const float w = wgt[t][k];
            #pragma unroll
            for (int j = 0; j < 4; ++j) {
                const unsigned int uu = vv[j];
                acc[t][2*j+0] = fmaf(__uint_as_float(uu << 16),         w, acc[t][2*j+0]);
                acc[t][2*j+1] = fmaf(__uint_as_float(uu & 0xffff0000u), w, acc[t][2*j+1]);
            }
        }
    }

    float* obase = out + (size_t)bv * Cc * N + (size_t)(8 * q) * N + n0;
    #pragma unroll
    for (int j = 0; j < 8; ++j) {
        fx2 o = { acc[0][j], acc[1][j] };
        __builtin_nontemporal_store(o, (fx2*)&obase[(size_t)j * N]);
    }
}

// 1-pt/thread variant (odd N)
__global__ __launch_bounds__(BDIM) void gather_kernel(
    const unsigned short* __restrict__ ws,
    const float* __restrict__ pts,
    const float* __restrict__ Kmat,
    const float* __restrict__ Emat,
    float* __restrict__ out,
    int N)
{
    const int bv  = blockIdx.y;
    const int b   = bv >> 2;
    const int tid = threadIdx.x;
    const int q   = tid & 3;
    const int n   = blockIdx.x * (BDIM / 4) + (tid >> 2);
    if (n >= N) return;

    int x0c, x1c, y0c, y1c; float wgt[4];
    project_point(Kmat + bv * 9, Emat + bv * 12,
                  pts[(size_t)(b * 3 + 0) * N + n],
                  pts[(size_t)(b * 3 + 1) * N + n],
                  pts[(size_t)(b * 3 + 2) * N + n],
                  x0c, x1c, y0c, y1c, wgt);
    const int idx[4] = { y0c * Ww + x0c, y0c * Ww + x1c,
                         y1c * Ww + x0c, y1c * Ww + x1c };

    const unsigned short* base = ws + (size_t)bv * HW * Cc + q * 8;
    float acc[8];
    #pragma unroll
    for (int j = 0; j < 8; ++j) acc[j] = 0.0f;

    #pragma unroll
    for (int k = 0; k < 4; ++k) {
        const ux4 vv = *(const ux4*)(base + (size_t)idx[k] * Cc);
        const float w = wgt[k];
        #pragma unroll
        for (int j = 0; j < 4; ++j) {
            const unsigned int uu = vv[j];
            acc[2*j+0] = fmaf(__uint_as_float(uu << 16),         w, acc[2*j+0]);
            acc[2*j+1] = fmaf(__uint_as_float(uu & 0xffff0000u), w, acc[2*j+1]);
        }
    }

    float* obase = out + (size_t)bv * Cc * N + (size_t)(8 * q) * N + n;
    #pragma unroll
    for (int j = 0; j < 8; ++j)
        __builtin_nontemporal_store(acc[j], &obase[(size_t)j * N]);
}

// full fallback (no workspace)
__global__ __launch_bounds__(BDIM) void feature_fetch_fallback(
    const float* __restrict__ fm, const float* __restrict__ pts,
    const float* __restrict__ Kmat, const float* __restrict__ Emat,
    float* __restrict__ out, int N)
{
    const int bv = blockIdx.y;
    const int b  = bv >> 2;
    const int n  = blockIdx.x * BDIM + threadIdx.x;
    if (n >= N) return;
    int x0c, x1c, y0c, y1c; float wgt[4];
    project_point(Kmat + bv * 9, Emat + bv * 12,
                  pts[(size_t)(b * 3 + 0) * N + n],
                  pts[(size_t)(b * 3 + 1) * N + n],
                  pts[(size_t)(b * 3 + 2) * N + n],
                  x0c, x1c, y0c, y1c, wgt);
    const int idx[4] = { y0c * Ww + x0c, y0c * Ww + x1c,
                         y1c * Ww + x0c, y1c * Ww + x1c };
    const float* basep = fm + (size_t)bv * Cc * HW;
    float* obase = out + (size_t)bv * Cc * N + n;
    #pragma unroll 4
    for (int c = 0; c < Cc; ++c) {
        const float* p = basep + (size_t)c * HW;
        obase[(size_t)c * N] = p[idx[0]] * wgt[0] + p[idx[1]] * wgt[1]
                             + p[idx[2]] * wgt[2] + p[idx[3]] * wgt[3];
    }
}

extern "C" void kernel_launch(void* const* d_in, const int* in_sizes, int n_in,
                              void* d_out, int out_size, void* d_ws, size_t ws_size,
                              hipStream_t stream) {
    const float* fm  = (const float*)d_in[0];
    const float* pts = (const float*)d_in[1];
    const float* K   = (const float*)d_in[2];
    const float* E   = (const float*)d_in[3];
    float* out = (float*)d_out;
    const int N = in_sizes[1] / 6;   // pts is [B=2, 3, N]

    const size_t tiles_bytes = (size_t)NBV * HW * Cc * sizeof(unsigned short); // 160 MB
    const size_t bm_bytes    = (size_t)NBV * NTILE * sizeof(unsigned int);     // 10 KB

    if (ws_size >= tiles_bytes + bm_bytes) {
        unsigned short* ws = (unsigned short*)d_ws;
        unsigned int* bitmap = (unsigned int*)((char*)d_ws + tiles_bytes);

        hipMemsetAsync(bitmap, 0, bm_bytes, stream);
        const int per_block = 2048;
        dim3 mgrid((N + per_block - 1) / per_block, NBV);
        mark_kernel<<<mgrid, 256, 0, stream>>>(pts, K, E, bitmap, N, per_block);
        dim3 tgrid(NTILE, NBV);
        transpose_tiles_kernel<<<tgrid, 256, 0, stream>>>(fm, ws, bitmap);

        if ((N & 1) == 0) {
            const int ppb = (BDIM / 4) * 2;
            dim3 ggrid((N + ppb - 1) / ppb, NBV);
            gather2_kernel<<<ggrid, BDIM, 0, stream>>>(ws, pts, K, E, out, N);
        } else {
            const int ppb = BDIM / 4;
            dim3 ggrid((N + ppb - 1) / ppb, NBV);
            gather_kernel<<<ggrid, BDIM, 0, stream>>>(ws, pts, K, E, out, N);
        }
    } else if (ws_size >= tiles_bytes) {
        unsigned short* ws = (unsigned short*)d_ws;
        dim3 tgrid(HW / 256, NBV);
        transpose_kernel<<<tgrid, 256, 0, stream>>>(fm, ws);
        if ((N & 1) == 0) {
            const int ppb = (BDIM / 4) * 2;
            dim3 ggrid((N + ppb - 1) / ppb, NBV);
            gather2_kernel<<<ggrid, BDIM, 0, stream>>>(ws, pts, K, E, out, N);
        } else {
            const int ppb = BDIM / 4;
            dim3 ggrid((N + ppb - 1) / ppb, NBV);
            gather_kernel<<<ggrid, BDIM, 0, stream>>>(ws, pts, K, E, out, N);
        }
    } else {
        dim3 grid((N + BDIM - 1) / BDIM, NBV);
        feature_fetch_fallback<<<grid, BDIM, 0, stream>>>(fm, pts, K, E, out, N);
    }
}